// Round 3
// baseline (268.981 us; speedup 1.0000x reference)
//
#include <hip/hip_runtime.h>
#include <hip/hip_bf16.h>

// Problem constants (B=2,T=64,N=64,D_IN=512,HID=256,L=2,H=4,C=64)
#define BT_G   128
#define NND    64
#define D_IN_  512
#define HID_   256
#define NH     4
#define NCH    64
#define NROWS  8192
#define LN_EPS_    1e-5f

typedef __hip_bfloat16 bf16;
typedef __attribute__((ext_vector_type(8))) short short8;   // 8 bf16 = 4 VGPRs
typedef __attribute__((ext_vector_type(4))) float float4v;  // MFMA C/D

__device__ __forceinline__ float toF(bf16 x) { return __bfloat162float(x); }

// ---------------------------------------------------------------------------
// z=0: W_in(512x256)->WTin[256][512]; z=1,2: Wl[li]->WlrT[li][0:256][256];
// z=3,4: Wr[li]->WlrT[li][256:512][256]; z=5 (block 0,0): mask canonicalize
// + zero the 256 per-graph epilogue counters (ws is poisoned between iters).
__global__ __launch_bounds__(256) void transpose_all_kernel(
    const float* __restrict__ W_in, const float* __restrict__ Wl,
    const float* __restrict__ Wr, const unsigned int* __restrict__ mw,
    bf16* __restrict__ WTin, bf16* __restrict__ WlrT, int* __restrict__ mout,
    int* __restrict__ cnt) {
    const int z = blockIdx.z;
    const int tid = threadIdx.x;
    if (z == 5) {
        if (blockIdx.x || blockIdx.y) return;
        if (tid < 256) cnt[tid] = 0;
        __shared__ int okInt, okF32, okB16, okByte;
        if (tid == 0) { okInt = 1; okF32 = 1; okB16 = 1; okByte = 1; }
        __syncthreads();
        int aI = 1, aF = 1, aB = 1, aC = 1;
        for (int i = tid; i < 2048; i += 256) {   // 8 KB probe — safe all layouts
            unsigned w = mw[i];
            aI &= (w <= 1u);
            aF &= (w == 0u || w == 0x3F800000u);
            unsigned lo = w & 0xFFFFu, hi = w >> 16;
            aB &= ((lo == 0u || lo == 0x3F80u) && (hi == 0u || hi == 0x3F80u));
            aC &= (((w | (w >> 8) | (w >> 16) | (w >> 24)) & 0xFEu) == 0u);
        }
        if (!aI) atomicAnd(&okInt, 0);
        if (!aF) atomicAnd(&okF32, 0);
        if (!aB) atomicAnd(&okB16, 0);
        if (!aC) atomicAnd(&okByte, 0);
        __syncthreads();
        const int layout = (okInt || okF32) ? 0 : (okB16 ? 2 : (okByte ? 3 : 0));
        for (int i = tid; i < NROWS; i += 256) {
            int v;
            if (layout == 2)      v = (((const unsigned short*)mw)[i] != 0);
            else if (layout == 3) v = (((const unsigned char*)mw)[i] != 0);
            else                  v = (mw[i] != 0u);
            mout[i] = v;
        }
        return;
    }
    __shared__ float t[32][33];
    const float* src; bf16* dst; int K;
    if (z == 0)      { src = W_in;                 dst = WTin;                    K = 512; }
    else if (z <= 2) { src = Wl + (z - 1) * 65536; dst = WlrT + (z - 1) * 131072; K = 256; }
    else             { src = Wr + (z - 3) * 65536; dst = WlrT + (z - 3) * 131072 + 256 * 256; K = 256; }
    const int n0 = blockIdx.x * 32, k0 = blockIdx.y * 32;
    if (k0 >= K) return;
    const int tx = tid & 31, ty = tid >> 5;
    #pragma unroll
    for (int i = 0; i < 4; ++i)
        t[ty + 8 * i][tx] = src[(size_t)(k0 + ty + 8 * i) * 256 + n0 + tx];
    __syncthreads();
    #pragma unroll
    for (int i = 0; i < 4; ++i)
        dst[(size_t)(n0 + ty + 8 * i) * K + k0 + tx] =
            __float2bfloat16(t[tx][ty + 8 * i]);
}

// ---------------------------------------------------------------------------
// Input GEMM: C[8192][256] = A_fp32[8192][512] @ WTin[256][512]^T + bias.
// Converts A to bf16 in-register during staging. Tile 64x64, BK=64,
// 4 waves 2x2 (each 32x32 via 2x2 mfma). Writes fp32 Cf + bf16 Cb16.
__global__ __launch_bounds__(256) void gemm_in_kernel(
    const float* __restrict__ A, const bf16* __restrict__ BT,
    const float* __restrict__ bias, float* __restrict__ Cf,
    bf16* __restrict__ Cb16)
{
    __shared__ bf16 As[64 * 72];
    __shared__ bf16 Bs[64 * 72];
    const int tid  = threadIdx.x;
    const int wave = tid >> 6, lane = tid & 63;
    const int quad = lane >> 4, l16 = lane & 15;
    const int m0 = blockIdx.y * 64, n0 = blockIdx.x * 64;
    const int wm = (wave & 1) * 32, wn = (wave >> 1) * 32;
    float4v acc[2][2] = {};
    const int r  = tid >> 2;
    const int cq = (tid & 3) * 16;

    for (int k0 = 0; k0 < D_IN_; k0 += 64) {
        const float* sa = A + (size_t)(m0 + r) * D_IN_ + k0 + cq;
        const float4 f0 = *(const float4*)(sa);
        const float4 f1 = *(const float4*)(sa + 4);
        const float4 f2 = *(const float4*)(sa + 8);
        const float4 f3 = *(const float4*)(sa + 12);
        const bf16* sb = BT + (size_t)(n0 + r) * D_IN_ + k0 + cq;
        const float4 b0 = *(const float4*)(sb);
        const float4 b1 = *(const float4*)(sb + 8);
        union { bf16 h[16]; float4 v[2]; } u;
        u.h[0]=__float2bfloat16(f0.x); u.h[1]=__float2bfloat16(f0.y);
        u.h[2]=__float2bfloat16(f0.z); u.h[3]=__float2bfloat16(f0.w);
        u.h[4]=__float2bfloat16(f1.x); u.h[5]=__float2bfloat16(f1.y);
        u.h[6]=__float2bfloat16(f1.z); u.h[7]=__float2bfloat16(f1.w);
        u.h[8]=__float2bfloat16(f2.x); u.h[9]=__float2bfloat16(f2.y);
        u.h[10]=__float2bfloat16(f2.z); u.h[11]=__float2bfloat16(f2.w);
        u.h[12]=__float2bfloat16(f3.x); u.h[13]=__float2bfloat16(f3.y);
        u.h[14]=__float2bfloat16(f3.z); u.h[15]=__float2bfloat16(f3.w);
        __syncthreads();
        *(float4*)(&As[r * 72 + cq])     = u.v[0];
        *(float4*)(&As[r * 72 + cq + 8]) = u.v[1];
        *(float4*)(&Bs[r * 72 + cq])     = b0;
        *(float4*)(&Bs[r * 72 + cq + 8]) = b1;
        __syncthreads();
        #pragma unroll
        for (int kk = 0; kk < 64; kk += 32) {
            short8 af[2], bf2[2];
            #pragma unroll
            for (int mi = 0; mi < 2; ++mi)
                af[mi] = *(const short8*)(&As[(wm + mi * 16 + l16) * 72 + kk + quad * 8]);
            #pragma unroll
            for (int ni = 0; ni < 2; ++ni)
                bf2[ni] = *(const short8*)(&Bs[(wn + ni * 16 + l16) * 72 + kk + quad * 8]);
            #pragma unroll
            for (int mi = 0; mi < 2; ++mi)
                #pragma unroll
                for (int ni = 0; ni < 2; ++ni)
                    acc[mi][ni] = __builtin_amdgcn_mfma_f32_16x16x32_bf16(
                        af[mi], bf2[ni], acc[mi][ni], 0, 0, 0);
        }
    }
    #pragma unroll
    for (int ni = 0; ni < 2; ++ni) {
        const int col = n0 + wn + ni * 16 + l16;
        const float bv = bias[col];
        #pragma unroll
        for (int mi = 0; mi < 2; ++mi)
            #pragma unroll
            for (int rr = 0; rr < 4; ++rr) {
                const int row = m0 + wm + mi * 16 + quad * 4 + rr;
                const float v = acc[mi][ni][rr] + bv;
                Cf[(size_t)row * HID_ + col] = v;
                Cb16[(size_t)row * HID_ + col] = __float2bfloat16(v);
            }
    }
}

// ---------------------------------------------------------------------------
// Fused xl|xr GEMM: C[M][512] = A[M][256](bf16) @ BT[512][256]^T + bias.
// Tile 128x64, BK=64; 4 waves 2x2, wave = 64x32 via 4x2 MFMA.
// col<256 -> Ca (+bias0) else Cbf (+bias1); both row-stride 256.
__global__ __launch_bounds__(256) void gemm_mfma_kernel(
    const bf16* __restrict__ A, const bf16* __restrict__ BT,
    const float* __restrict__ bias0, const float* __restrict__ bias1,
    float* __restrict__ Ca, float* __restrict__ Cbf, int M, int K)
{
    __shared__ bf16 As[128 * 72];
    __shared__ bf16 Bs[64 * 72];
    const int tid  = threadIdx.x;
    const int wave = tid >> 6, lane = tid & 63;
    const int quad = lane >> 4, l16 = lane & 15;
    const int m0 = blockIdx.y * 128, n0g = blockIdx.x * 64;
    const int wm = (wave & 1) * 64, wn = (wave >> 1) * 32;
    float4v acc[4][2] = {};
    const int r  = tid >> 2;
    const int cq = (tid & 3) * 16;

    for (int k0 = 0; k0 < K; k0 += 64) {
        const bf16* sa0 = A  + (size_t)(m0 + r) * K + k0 + cq;
        const bf16* sa1 = sa0 + (size_t)64 * K;
        const bf16* sb  = BT + (size_t)(n0g + r) * K + k0 + cq;
        const float4 a00 = *(const float4*)(sa0);
        const float4 a01 = *(const float4*)(sa0 + 8);
        const float4 a10 = *(const float4*)(sa1);
        const float4 a11 = *(const float4*)(sa1 + 8);
        const float4 b0  = *(const float4*)(sb);
        const float4 b1  = *(const float4*)(sb + 8);
        __syncthreads();
        *(float4*)(&As[r * 72 + cq])            = a00;
        *(float4*)(&As[r * 72 + cq + 8])        = a01;
        *(float4*)(&As[(r + 64) * 72 + cq])     = a10;
        *(float4*)(&As[(r + 64) * 72 + cq + 8]) = a11;
        *(float4*)(&Bs[r * 72 + cq])            = b0;
        *(float4*)(&Bs[r * 72 + cq + 8])        = b1;
        __syncthreads();
        #pragma unroll
        for (int kk = 0; kk < 64; kk += 32) {
            short8 af[4], bf2[2];
            #pragma unroll
            for (int mi = 0; mi < 4; ++mi)
                af[mi] = *(const short8*)(&As[(wm + mi * 16 + l16) * 72 + kk + quad * 8]);
            #pragma unroll
            for (int ni = 0; ni < 2; ++ni)
                bf2[ni] = *(const short8*)(&Bs[(wn + ni * 16 + l16) * 72 + kk + quad * 8]);
            #pragma unroll
            for (int mi = 0; mi < 4; ++mi)
                #pragma unroll
                for (int ni = 0; ni < 2; ++ni)
                    acc[mi][ni] = __builtin_amdgcn_mfma_f32_16x16x32_bf16(
                        af[mi], bf2[ni], acc[mi][ni], 0, 0, 0);
        }
    }
    const bool loHalf = (n0g < 256);
    float* Co = loHalf ? Ca : Cbf;
    const float* bp = loHalf ? bias0 : bias1;
    const int cbase = loHalf ? n0g : (n0g - 256);
    #pragma unroll
    for (int ni = 0; ni < 2; ++ni) {
        const int col = cbase + wn + ni * 16 + l16;
        const float bv = bp[col];
        #pragma unroll
        for (int mi = 0; mi < 4; ++mi)
            #pragma unroll
            for (int rr = 0; rr < 4; ++rr) {
                const int row = m0 + wm + mi * 16 + quad * 4 + rr;
                Co[(size_t)row * 256 + col] = acc[mi][ni][rr] + bv;
            }
    }
}

// ---------------------------------------------------------------------------
// GATv2 attention per (graph, head), 4x4-tiled, b128 LDS reads — round-0
// verified structure (512 blocks, 2 blocks/CU). After writing its g slice,
// each block bumps a per-graph counter; the 4th arriver runs the epilogue
// (ELU->LN->+res->mask) for the whole graph — identical arithmetic to the
// old epilogue_kernel. g MAY ALIAS xr (disjoint per-graph slices).
__global__ __launch_bounds__(256) void attn_kernel(
    const float* xl, const float* xr, const float* att,
    const int* msk, float* g,
    int* __restrict__ cnt, const float* __restrict__ res,
    const float* __restrict__ ob, const float* __restrict__ lns,
    const float* __restrict__ lnb, float* __restrict__ hout,
    bf16* __restrict__ hb, int finalSel)
{
    __shared__ float xls [64][68];   // xl row-major [j][c]   (phase 3)
    __shared__ float xlsT[64][68];   // [c][j]                (phase 1)
    __shared__ float xrsT[64][68];   // [c][i]                (phase 1)
    __shared__ float esT [64][68];   // [j][i]
    __shared__ float av[64], P[64], Q[64], mxf[64], inv[64];
    __shared__ float pmax[4][64], psum[4][64];
    __shared__ int   ms[64];
    __shared__ int   lastF;
    const int tid  = threadIdx.x;
    const int head = blockIdx.x, gr = blockIdx.y;
    const int ti = tid >> 4, tj = tid & 15;       // 16x16 thread grid
    const int i0 = ti * 4, j0 = tj * 4;           // 4x4 tile
    const float* xlg = xl + (size_t)gr * NND * HID_ + head * NCH;
    const float* xrg = xr + (size_t)gr * NND * HID_ + head * NCH;

    // ---- staging: 16 elems/thread of xl (both layouts) and xr (transposed)
    {
        const int r  = tid >> 2;
        const int c0 = (tid & 3) * 16;
        float a[4][4], b[4][4];
        #pragma unroll
        for (int k = 0; k < 4; ++k) {
            *(float4*)a[k] = *(const float4*)(xlg + r * HID_ + c0 + 4 * k);
            *(float4*)b[k] = *(const float4*)(xrg + r * HID_ + c0 + 4 * k);
        }
        #pragma unroll
        for (int k = 0; k < 4; ++k)
            *(float4*)&xls[r][c0 + 4 * k] = *(float4*)a[k];
        #pragma unroll
        for (int k = 0; k < 4; ++k)
            #pragma unroll
            for (int w = 0; w < 4; ++w) {
                xlsT[c0 + 4 * k + w][r] = a[k][w];
                xrsT[c0 + 4 * k + w][r] = b[k][w];
            }
    }
    if (tid < 64) {
        av[tid] = att[head * NCH + tid];
        ms[tid] = msk[gr * NND + tid];
    }
    __syncthreads();

    // ---- phase 1: abs-sum accumulation, 2 x b128 per c
    float aa[4][4] = {};
    for (int c = 0; c < 64; ++c) {
        float xr4[4], xl4[4];
        *(float4*)xr4 = *(const float4*)&xrsT[c][i0];
        *(float4*)xl4 = *(const float4*)&xlsT[c][j0];
        const float a = av[c];
        #pragma unroll
        for (int y = 0; y < 4; ++y)
            #pragma unroll
            for (int x = 0; x < 4; ++x)
                aa[y][x] = fmaf(a, fabsf(xr4[y] + xl4[x]), aa[y][x]);
    }
    // P/Q by waves 0 and 1 (xlsT/xrsT stable since staging barrier)
    if (tid < 64) {
        float s = 0.f;
        for (int c = 0; c < 64; ++c) s = fmaf(av[c], xrsT[c][tid], s);
        P[tid] = s;
    } else if (tid < 128) {
        const int j = tid - 64;
        float s = 0.f;
        for (int c = 0; c < 64; ++c) s = fmaf(av[c], xlsT[c][j], s);
        Q[j] = s;
    }
    __syncthreads();

    // ---- combine, mask, write esT[j][i]
    {
        float Pv[4], Qv[4]; int mi4[4], mj4[4];
        #pragma unroll
        for (int y = 0; y < 4; ++y) { Pv[y] = P[i0 + y]; mi4[y] = ms[i0 + y]; }
        #pragma unroll
        for (int x = 0; x < 4; ++x) { Qv[x] = Q[j0 + x]; mj4[x] = ms[j0 + x]; }
        #pragma unroll
        for (int x = 0; x < 4; ++x) {
            float col[4];
            #pragma unroll
            for (int y = 0; y < 4; ++y) {
                float e = fmaf(0.4f, aa[y][x], 0.6f * (Pv[y] + Qv[x]));
                const bool allowed = (mi4[y] && mj4[x]) || (i0 + y == j0 + x);
                col[y] = allowed ? e : -1e9f;
            }
            *(float4*)&esT[j0 + x][i0] = *(float4*)col;
        }
    }
    __syncthreads();

    // ---- softmax over j per row i (parallel: thread (q,i) handles 16 j's)
    {
        const int si = tid & 63, q = tid >> 6;
        float mx = -1e30f;
        #pragma unroll
        for (int k = 0; k < 16; ++k) mx = fmaxf(mx, esT[16 * q + k][si]);
        pmax[q][si] = mx;
    }
    __syncthreads();
    if (tid < 64)
        mxf[tid] = fmaxf(fmaxf(pmax[0][tid], pmax[1][tid]),
                         fmaxf(pmax[2][tid], pmax[3][tid]));
    __syncthreads();
    {
        const int si = tid & 63, q = tid >> 6;
        const float mx = mxf[si];
        float s = 0.f;
        #pragma unroll
        for (int k = 0; k < 16; ++k) {
            const float ev = __expf(esT[16 * q + k][si] - mx);
            esT[16 * q + k][si] = ev;
            s += ev;
        }
        psum[q][si] = s;
    }
    __syncthreads();
    if (tid < 64)
        inv[tid] = 1.f / (psum[0][tid] + psum[1][tid] + psum[2][tid] + psum[3][tid]);
    __syncthreads();

    // ---- phase 3: out[i][c] = inv[i] * sum_j w[j][i] * xl[j][c]
    {
        const int c0 = j0;             // reuse 4x4 grid: cols = channels
        float oa[4][4] = {};
        for (int j = 0; j < 64; ++j) {
            float al[4], xv[4];
            *(float4*)al = *(const float4*)&esT[j][i0];
            *(float4*)xv = *(const float4*)&xls[j][c0];
            #pragma unroll
            for (int y = 0; y < 4; ++y)
                #pragma unroll
                for (int x = 0; x < 4; ++x)
                    oa[y][x] = fmaf(al[y], xv[x], oa[y][x]);
        }
        #pragma unroll
        for (int y = 0; y < 4; ++y) {
            const float iv = inv[i0 + y];
            float o[4];
            #pragma unroll
            for (int x = 0; x < 4; ++x) o[x] = oa[y][x] * iv;
            float* go = g + (size_t)(gr * NND + i0 + y) * HID_ + head * NCH + c0;
            *(float4*)go = *(float4*)o;
        }
    }

    // ---- last-block-per-graph fused epilogue ------------------------------
    __syncthreads();                 // all g stores complete (waitcnt+barrier)
    if (tid == 0) {
        __threadfence();             // release: make this block's g visible
        lastF = (atomicAdd(&cnt[gr], 1) == 3);
    }
    __syncthreads();
    if (!lastF) return;
    __threadfence();                 // acquire: invalidate stale cached g
    if (finalSel) {
        int s = 0;
        #pragma unroll
        for (int k = 0; k < 64; ++k) s += (ms[k] != 0);
        if (s <= 1) return;          // leave h0 rows in hout (uniform branch)
    }
    const int lane = tid & 63, wv = tid >> 6;
    for (int rr = wv; rr < 64; rr += 4) {
        const int m = gr * NND + rr;
        const float* grow = g + (size_t)m * HID_;
        float v[4];
        float sum = 0.f;
        #pragma unroll
        for (int q = 0; q < 4; ++q) {
            const int c = q * 64 + lane;
            float x = grow[c] + ob[c];
            x = x > 0.f ? x : (__expf(x) - 1.f);   // ELU (alpha=1)
            v[q] = x; sum += x;
        }
        #pragma unroll
        for (int off = 1; off < 64; off <<= 1) sum += __shfl_xor(sum, off);
        const float mu = sum * (1.f / 256.f);
        float vs = 0.f;
        #pragma unroll
        for (int q = 0; q < 4; ++q) { const float d = v[q] - mu; vs += d * d; }
        #pragma unroll
        for (int off = 1; off < 64; off <<= 1) vs += __shfl_xor(vs, off);
        const float rstd = rsqrtf(vs * (1.f / 256.f) + LN_EPS_);
        const int mnode = ms[rr];
        const float* rrow = res + (size_t)m * HID_;
        float* ho = hout + (size_t)m * HID_;
        #pragma unroll
        for (int q = 0; q < 4; ++q) {
            const int c = q * 64 + lane;
            float y = (v[q] - mu) * rstd * lns[c] + lnb[c];
            y += rrow[c];
            y = mnode ? y : 0.f;
            ho[c] = y;
            if (hb) hb[(size_t)m * HID_ + c] = __float2bfloat16(y);
        }
    }
}

// ---------------------------------------------------------------------------
extern "C" void kernel_launch(void* const* d_in, const int* in_sizes, int n_in,
                              void* d_out, int out_size, void* d_ws, size_t ws_size,
                              hipStream_t stream) {
    const float* x    = (const float*)d_in[0];
    const float* W_in = (const float*)d_in[2];
    const float* b_in = (const float*)d_in[3];
    const float* Wl   = (const float*)d_in[4];
    const float* bl   = (const float*)d_in[5];
    const float* Wr   = (const float*)d_in[6];
    const float* br   = (const float*)d_in[7];
    const float* att  = (const float*)d_in[8];
    const float* ob   = (const float*)d_in[9];
    const float* lns  = (const float*)d_in[10];
    const float* lnb  = (const float*)d_in[11];
    float* out = (float*)d_out;

    // ws (~29 MB): [mcan 32K][cnt 1K][h 8M][xlb 8M][xrb 8M][hxb 4M][WTin][WlrT]
    char* w = (char*)d_ws;
    int*   mcan = (int*)w;                      w += 32768;
    int*   cnt  = (int*)w;                      w += 1024;    // 256 ints, 2 layers
    float* h    = (float*)w;                    w += (size_t)NROWS * HID_ * 4;
    float* xlb  = (float*)w;                    w += (size_t)NROWS * HID_ * 4;
    float* xrb  = (float*)w;                    w += (size_t)NROWS * HID_ * 4;
    bf16*  hxb  = (bf16*)w;                     w += (size_t)NROWS * HID_ * 2;
    bf16*  WTin = (bf16*)w;                     w += (size_t)D_IN_ * HID_ * 2;
    bf16*  WlrT = (bf16*)w;                     // [L][512][256]
    float* gb   = xrb;                          // aliased (safe — see attn_kernel)

    transpose_all_kernel<<<dim3(8, 16, 6), 256, 0, stream>>>(
        W_in, Wl, Wr, (const unsigned int*)d_in[1], WTin, WlrT, mcan, cnt);

    // d_out <- fp32 h0 = x @ W_in + b_in ; hxb <- bf16(h0)
    gemm_in_kernel<<<dim3(HID_ / 64, NROWS / 64), 256, 0, stream>>>(
        x, WTin, b_in, out, hxb);

    for (int li = 0; li < 2; ++li) {
        const float* resf = (li == 0) ? out : h;   // fp32 residual
        gemm_mfma_kernel<<<dim3(512 / 64, NROWS / 128), 256, 0, stream>>>(
            hxb, WlrT + (size_t)li * 512 * HID_, bl + li * HID_, br + li * HID_,
            xlb, xrb, NROWS, HID_);
        if (li == 0) {
            attn_kernel<<<dim3(NH, BT_G), 256, 0, stream>>>(
                xlb, xrb, att, mcan, gb,
                cnt, resf, ob, lns, lnb, h, hxb, 0);
        } else {
            attn_kernel<<<dim3(NH, BT_G), 256, 0, stream>>>(
                xlb, xrb, att + NH * NCH, mcan, gb,
                cnt + 128, resf, ob + HID_, lns + HID_, lnb + HID_,
                out, (bf16*)nullptr, 1);
        }
    }

    (void)in_sizes; (void)n_in; (void)out_size; (void)ws_size;
}

// Round 4
// 178.939 us; speedup vs baseline: 1.5032x; 1.5032x over previous
//
#include <hip/hip_runtime.h>
#include <hip/hip_bf16.h>

// Problem constants (B=2,T=64,N=64,D_IN=512,HID=256,L=2,H=4,C=64)
#define BT_G   128
#define NND    64
#define D_IN_  512
#define HID_   256
#define NH     4
#define NCH    64
#define NROWS  8192
#define LN_EPS_    1e-5f

typedef __hip_bfloat16 bf16;
typedef __attribute__((ext_vector_type(8))) short short8;   // 8 bf16 = 4 VGPRs
typedef __attribute__((ext_vector_type(4))) float float4v;  // MFMA C/D

__device__ __forceinline__ float toF(bf16 x) { return __bfloat162float(x); }

// ---------------------------------------------------------------------------
// z=0: W_in(512x256)->WTin[256][512]; z=1,2: Wl[li]->WlrT[li][0:256][256];
// z=3,4: Wr[li]->WlrT[li][256:512][256]; z=5 (block 0,0): mask canonicalize.
__global__ __launch_bounds__(256) void transpose_all_kernel(
    const float* __restrict__ W_in, const float* __restrict__ Wl,
    const float* __restrict__ Wr, const unsigned int* __restrict__ mw,
    bf16* __restrict__ WTin, bf16* __restrict__ WlrT, int* __restrict__ mout) {
    const int z = blockIdx.z;
    const int tid = threadIdx.x;
    if (z == 5) {
        if (blockIdx.x || blockIdx.y) return;
        __shared__ int okInt, okF32, okB16, okByte;
        if (tid == 0) { okInt = 1; okF32 = 1; okB16 = 1; okByte = 1; }
        __syncthreads();
        int aI = 1, aF = 1, aB = 1, aC = 1;
        for (int i = tid; i < 2048; i += 256) {   // 8 KB probe — safe all layouts
            unsigned w = mw[i];
            aI &= (w <= 1u);
            aF &= (w == 0u || w == 0x3F800000u);
            unsigned lo = w & 0xFFFFu, hi = w >> 16;
            aB &= ((lo == 0u || lo == 0x3F80u) && (hi == 0u || hi == 0x3F80u));
            aC &= (((w | (w >> 8) | (w >> 16) | (w >> 24)) & 0xFEu) == 0u);
        }
        if (!aI) atomicAnd(&okInt, 0);
        if (!aF) atomicAnd(&okF32, 0);
        if (!aB) atomicAnd(&okB16, 0);
        if (!aC) atomicAnd(&okByte, 0);
        __syncthreads();
        const int layout = (okInt || okF32) ? 0 : (okB16 ? 2 : (okByte ? 3 : 0));
        for (int i = tid; i < NROWS; i += 256) {
            int v;
            if (layout == 2)      v = (((const unsigned short*)mw)[i] != 0);
            else if (layout == 3) v = (((const unsigned char*)mw)[i] != 0);
            else                  v = (mw[i] != 0u);
            mout[i] = v;
        }
        return;
    }
    __shared__ float t[32][33];
    const float* src; bf16* dst; int K;
    if (z == 0)      { src = W_in;                 dst = WTin;                    K = 512; }
    else if (z <= 2) { src = Wl + (z - 1) * 65536; dst = WlrT + (z - 1) * 131072; K = 256; }
    else             { src = Wr + (z - 3) * 65536; dst = WlrT + (z - 3) * 131072 + 256 * 256; K = 256; }
    const int n0 = blockIdx.x * 32, k0 = blockIdx.y * 32;
    if (k0 >= K) return;
    const int tx = tid & 31, ty = tid >> 5;
    #pragma unroll
    for (int i = 0; i < 4; ++i)
        t[ty + 8 * i][tx] = src[(size_t)(k0 + ty + 8 * i) * 256 + n0 + tx];
    __syncthreads();
    #pragma unroll
    for (int i = 0; i < 4; ++i)
        dst[(size_t)(n0 + ty + 8 * i) * K + k0 + tx] =
            __float2bfloat16(t[tx][ty + 8 * i]);
}

// ---------------------------------------------------------------------------
// Input GEMM: C[8192][256] = A_fp32[8192][512] @ WTin[256][512]^T + bias.
// Converts A to bf16 in-register during staging. Tile 64x64, BK=64,
// 4 waves 2x2 (each 32x32 via 2x2 mfma). Writes fp32 Cf + bf16 Cb16.
__global__ __launch_bounds__(256) void gemm_in_kernel(
    const float* __restrict__ A, const bf16* __restrict__ BT,
    const float* __restrict__ bias, float* __restrict__ Cf,
    bf16* __restrict__ Cb16)
{
    __shared__ bf16 As[64 * 72];
    __shared__ bf16 Bs[64 * 72];
    const int tid  = threadIdx.x;
    const int wave = tid >> 6, lane = tid & 63;
    const int quad = lane >> 4, l16 = lane & 15;
    const int m0 = blockIdx.y * 64, n0 = blockIdx.x * 64;
    const int wm = (wave & 1) * 32, wn = (wave >> 1) * 32;
    float4v acc[2][2] = {};
    const int r  = tid >> 2;
    const int cq = (tid & 3) * 16;

    for (int k0 = 0; k0 < D_IN_; k0 += 64) {
        const float* sa = A + (size_t)(m0 + r) * D_IN_ + k0 + cq;
        const float4 f0 = *(const float4*)(sa);
        const float4 f1 = *(const float4*)(sa + 4);
        const float4 f2 = *(const float4*)(sa + 8);
        const float4 f3 = *(const float4*)(sa + 12);
        const bf16* sb = BT + (size_t)(n0 + r) * D_IN_ + k0 + cq;
        const float4 b0 = *(const float4*)(sb);
        const float4 b1 = *(const float4*)(sb + 8);
        union { bf16 h[16]; float4 v[2]; } u;
        u.h[0]=__float2bfloat16(f0.x); u.h[1]=__float2bfloat16(f0.y);
        u.h[2]=__float2bfloat16(f0.z); u.h[3]=__float2bfloat16(f0.w);
        u.h[4]=__float2bfloat16(f1.x); u.h[5]=__float2bfloat16(f1.y);
        u.h[6]=__float2bfloat16(f1.z); u.h[7]=__float2bfloat16(f1.w);
        u.h[8]=__float2bfloat16(f2.x); u.h[9]=__float2bfloat16(f2.y);
        u.h[10]=__float2bfloat16(f2.z); u.h[11]=__float2bfloat16(f2.w);
        u.h[12]=__float2bfloat16(f3.x); u.h[13]=__float2bfloat16(f3.y);
        u.h[14]=__float2bfloat16(f3.z); u.h[15]=__float2bfloat16(f3.w);
        __syncthreads();
        *(float4*)(&As[r * 72 + cq])     = u.v[0];
        *(float4*)(&As[r * 72 + cq + 8]) = u.v[1];
        *(float4*)(&Bs[r * 72 + cq])     = b0;
        *(float4*)(&Bs[r * 72 + cq + 8]) = b1;
        __syncthreads();
        #pragma unroll
        for (int kk = 0; kk < 64; kk += 32) {
            short8 af[2], bf2[2];
            #pragma unroll
            for (int mi = 0; mi < 2; ++mi)
                af[mi] = *(const short8*)(&As[(wm + mi * 16 + l16) * 72 + kk + quad * 8]);
            #pragma unroll
            for (int ni = 0; ni < 2; ++ni)
                bf2[ni] = *(const short8*)(&Bs[(wn + ni * 16 + l16) * 72 + kk + quad * 8]);
            #pragma unroll
            for (int mi = 0; mi < 2; ++mi)
                #pragma unroll
                for (int ni = 0; ni < 2; ++ni)
                    acc[mi][ni] = __builtin_amdgcn_mfma_f32_16x16x32_bf16(
                        af[mi], bf2[ni], acc[mi][ni], 0, 0, 0);
        }
    }
    #pragma unroll
    for (int ni = 0; ni < 2; ++ni) {
        const int col = n0 + wn + ni * 16 + l16;
        const float bv = bias[col];
        #pragma unroll
        for (int mi = 0; mi < 2; ++mi)
            #pragma unroll
            for (int rr = 0; rr < 4; ++rr) {
                const int row = m0 + wm + mi * 16 + quad * 4 + rr;
                const float v = acc[mi][ni][rr] + bv;
                Cf[(size_t)row * HID_ + col] = v;
                Cb16[(size_t)row * HID_ + col] = __float2bfloat16(v);
            }
    }
}

// ---------------------------------------------------------------------------
// Fused xl|xr GEMM: C[M][512] = A[M][256](bf16) @ BT[512][256]^T + bias.
// Tile 128x64, BK=64; 4 waves 2x2, wave = 64x32 via 4x2 MFMA.
// col<256 -> Ca (+bias0) else Cbf (+bias1); both row-stride 256.
__global__ __launch_bounds__(256) void gemm_mfma_kernel(
    const bf16* __restrict__ A, const bf16* __restrict__ BT,
    const float* __restrict__ bias0, const float* __restrict__ bias1,
    float* __restrict__ Ca, float* __restrict__ Cbf, int M, int K)
{
    __shared__ bf16 As[128 * 72];
    __shared__ bf16 Bs[64 * 72];
    const int tid  = threadIdx.x;
    const int wave = tid >> 6, lane = tid & 63;
    const int quad = lane >> 4, l16 = lane & 15;
    const int m0 = blockIdx.y * 128, n0g = blockIdx.x * 64;
    const int wm = (wave & 1) * 64, wn = (wave >> 1) * 32;
    float4v acc[4][2] = {};
    const int r  = tid >> 2;
    const int cq = (tid & 3) * 16;

    for (int k0 = 0; k0 < K; k0 += 64) {
        const bf16* sa0 = A  + (size_t)(m0 + r) * K + k0 + cq;
        const bf16* sa1 = sa0 + (size_t)64 * K;
        const bf16* sb  = BT + (size_t)(n0g + r) * K + k0 + cq;
        const float4 a00 = *(const float4*)(sa0);
        const float4 a01 = *(const float4*)(sa0 + 8);
        const float4 a10 = *(const float4*)(sa1);
        const float4 a11 = *(const float4*)(sa1 + 8);
        const float4 b0  = *(const float4*)(sb);
        const float4 b1  = *(const float4*)(sb + 8);
        __syncthreads();
        *(float4*)(&As[r * 72 + cq])            = a00;
        *(float4*)(&As[r * 72 + cq + 8])        = a01;
        *(float4*)(&As[(r + 64) * 72 + cq])     = a10;
        *(float4*)(&As[(r + 64) * 72 + cq + 8]) = a11;
        *(float4*)(&Bs[r * 72 + cq])            = b0;
        *(float4*)(&Bs[r * 72 + cq + 8])        = b1;
        __syncthreads();
        #pragma unroll
        for (int kk = 0; kk < 64; kk += 32) {
            short8 af[4], bf2[2];
            #pragma unroll
            for (int mi = 0; mi < 4; ++mi)
                af[mi] = *(const short8*)(&As[(wm + mi * 16 + l16) * 72 + kk + quad * 8]);
            #pragma unroll
            for (int ni = 0; ni < 2; ++ni)
                bf2[ni] = *(const short8*)(&Bs[(wn + ni * 16 + l16) * 72 + kk + quad * 8]);
            #pragma unroll
            for (int mi = 0; mi < 4; ++mi)
                #pragma unroll
                for (int ni = 0; ni < 2; ++ni)
                    acc[mi][ni] = __builtin_amdgcn_mfma_f32_16x16x32_bf16(
                        af[mi], bf2[ni], acc[mi][ni], 0, 0, 0);
        }
    }
    const bool loHalf = (n0g < 256);
    float* Co = loHalf ? Ca : Cbf;
    const float* bp = loHalf ? bias0 : bias1;
    const int cbase = loHalf ? n0g : (n0g - 256);
    #pragma unroll
    for (int ni = 0; ni < 2; ++ni) {
        const int col = cbase + wn + ni * 16 + l16;
        const float bv = bp[col];
        #pragma unroll
        for (int mi = 0; mi < 4; ++mi)
            #pragma unroll
            for (int rr = 0; rr < 4; ++rr) {
                const int row = m0 + wm + mi * 16 + quad * 4 + rr;
                Co[(size_t)row * 256 + col] = acc[mi][ni][rr] + bv;
            }
    }
}

// ---------------------------------------------------------------------------
// GATv2 attention per (graph, head, i-half): grid (NH*2, BT_G), 1024 blocks.
// Each block computes 32 target rows (i in [half*32, half*32+32)) against all
// 64 sources j, for one head. Phase code identical to the round-2-verified
// attn_ep inner loop. LDS 47 KB -> 3 blocks/CU. esT overlays xlsT (dead after
// phase 1). g MAY ALIAS xr: each (row,col) of xr is read only by the block
// that writes it, and its reads precede its writes.
__global__ __launch_bounds__(256) void attn_kernel(
    const float* xl, const float* xr, const float* att,
    const int* msk, float* g)
{
    __shared__ float xls [64][68];   // xl row-major [j][c]   (phase 3)
    __shared__ float xlsT[64][68];   // [c][j] (phase 1); esT[64][36] after
    __shared__ float xrsT[64][36];   // [c][i]  (32 i-rows)   (phase 1)
    __shared__ float av[64], P[32], Q[64], mxf[32], inv[32];
    __shared__ float pmax[8][32], psum[8][32];
    __shared__ int   ms[64];
    float (*esT)[36] = (float(*)[36])xlsT;   // overlay: xlsT dead after phase 1

    const int tid   = threadIdx.x;
    const int head  = blockIdx.x >> 1;
    const int half  = blockIdx.x & 1;
    const int gr    = blockIdx.y;
    const int ibase = half * 32;
    const int ti = tid >> 4, tj = tid & 15;   // 16x16 thread grid
    const int i0 = ti * 2, j0 = tj * 4;       // 2x4 tile (i half-range)

    const float* xlg = xl + (size_t)gr * NND * HID_ + head * NCH;
    const float* xrg = xr + ((size_t)gr * NND + ibase) * HID_ + head * NCH;

    // ---- staging: xl 64x64 (both layouts), xr 32x64 (transposed), att row
    {
        const int r  = tid >> 2;
        const int c0 = (tid & 3) * 16;
        const int r2 = tid >> 3;
        const int cb = (tid & 7) * 8;
        float a[4][4], b[2][4];
        #pragma unroll
        for (int k = 0; k < 4; ++k)
            *(float4*)a[k] = *(const float4*)(xlg + r * HID_ + c0 + 4 * k);
        *(float4*)b[0] = *(const float4*)(xrg + r2 * HID_ + cb);
        *(float4*)b[1] = *(const float4*)(xrg + r2 * HID_ + cb + 4);
        #pragma unroll
        for (int k = 0; k < 4; ++k)
            *(float4*)&xls[r][c0 + 4 * k] = *(float4*)a[k];
        #pragma unroll
        for (int k = 0; k < 4; ++k)
            #pragma unroll
            for (int w = 0; w < 4; ++w)
                xlsT[c0 + 4 * k + w][r] = a[k][w];
        #pragma unroll
        for (int k = 0; k < 2; ++k)
            #pragma unroll
            for (int w = 0; w < 4; ++w)
                xrsT[cb + 4 * k + w][r2] = b[k][w];
        if (tid < 64) {
            av[tid] = att[head * NCH + tid];
            ms[tid] = msk[gr * NND + tid];
        }
    }
    __syncthreads();

    // ---- phase 1: abs-sum accumulation over c (2x4 tile per thread)
    float aa[2][4] = {};
    for (int c = 0; c < 64; ++c) {
        const float a = av[c];
        const float2 xr2 = *(const float2*)&xrsT[c][i0];
        const float4 xl4 = *(const float4*)&xlsT[c][j0];
        const float xrv[2] = {xr2.x, xr2.y};
        const float xlv[4] = {xl4.x, xl4.y, xl4.z, xl4.w};
        #pragma unroll
        for (int y = 0; y < 2; ++y)
            #pragma unroll
            for (int x = 0; x < 4; ++x)
                aa[y][x] = fmaf(a, fabsf(xrv[y] + xlv[x]), aa[y][x]);
    }
    if (tid < 32) {
        float s = 0.f;
        for (int c = 0; c < 64; ++c) s = fmaf(av[c], xrsT[c][tid], s);
        P[tid] = s;
    } else if (tid >= 64 && tid < 128) {
        const int j = tid - 64;
        float s = 0.f;
        for (int c = 0; c < 64; ++c) s = fmaf(av[c], xlsT[c][j], s);
        Q[j] = s;
    }
    __syncthreads();

    // ---- combine, mask, write esT[j][i] (esT overlays dead xlsT)
    {
        float Pv[2], Qv[4]; int mi2[2], mj4[4];
        #pragma unroll
        for (int y = 0; y < 2; ++y) { Pv[y] = P[i0 + y]; mi2[y] = ms[ibase + i0 + y]; }
        #pragma unroll
        for (int x = 0; x < 4; ++x) { Qv[x] = Q[j0 + x]; mj4[x] = ms[j0 + x]; }
        #pragma unroll
        for (int x = 0; x < 4; ++x) {
            float col[2];
            #pragma unroll
            for (int y = 0; y < 2; ++y) {
                float e = fmaf(0.4f, aa[y][x], 0.6f * (Pv[y] + Qv[x]));
                const bool allowed = (mi2[y] && mj4[x]) || (ibase + i0 + y == j0 + x);
                col[y] = allowed ? e : -1e9f;
            }
            *(float2*)&esT[j0 + x][i0] = *(float2*)col;
        }
    }
    __syncthreads();

    // ---- softmax over j per row i (8 threads per i, 8 j's each)
    {
        const int si = tid & 31, q = tid >> 5;
        float mx = -1e30f;
        #pragma unroll
        for (int k = 0; k < 8; ++k) mx = fmaxf(mx, esT[8 * q + k][si]);
        pmax[q][si] = mx;
    }
    __syncthreads();
    if (tid < 32) {
        float m = pmax[0][tid];
        #pragma unroll
        for (int q = 1; q < 8; ++q) m = fmaxf(m, pmax[q][tid]);
        mxf[tid] = m;
    }
    __syncthreads();
    {
        const int si = tid & 31, q = tid >> 5;
        const float mx = mxf[si];
        float s = 0.f;
        #pragma unroll
        for (int k = 0; k < 8; ++k) {
            const float ev = __expf(esT[8 * q + k][si] - mx);
            esT[8 * q + k][si] = ev;
            s += ev;
        }
        psum[q][si] = s;
    }
    __syncthreads();
    if (tid < 32) {
        float s = psum[0][tid];
        #pragma unroll
        for (int q = 1; q < 8; ++q) s += psum[q][tid];
        inv[tid] = 1.f / s;
    }
    __syncthreads();

    // ---- phase 3: g[ibase+i][head*64+c] = inv[i] * sum_j w[j][i] * xl[j][c]
    {
        float oa[2][4] = {};
        for (int j = 0; j < 64; ++j) {
            const float2 al = *(const float2*)&esT[j][i0];
            const float4 xv = *(const float4*)&xls[j][j0];
            const float alv[2] = {al.x, al.y};
            const float xvv[4] = {xv.x, xv.y, xv.z, xv.w};
            #pragma unroll
            for (int y = 0; y < 2; ++y)
                #pragma unroll
                for (int x = 0; x < 4; ++x)
                    oa[y][x] = fmaf(alv[y], xvv[x], oa[y][x]);
        }
        #pragma unroll
        for (int y = 0; y < 2; ++y) {
            const float iv = inv[i0 + y];
            float o[4];
            #pragma unroll
            for (int x = 0; x < 4; ++x) o[x] = oa[y][x] * iv;
            float* go = g + (size_t)(gr * NND + ibase + i0 + y) * HID_ + head * NCH + j0;
            *(float4*)go = *(float4*)o;
        }
    }
}

// ---------------------------------------------------------------------------
// g + ob -> ELU -> LayerNorm -> + res -> zero unmasked.
// finalSel=0: always write hout (+ optional bf16 mirror hb).
// finalSel=1: hout = d_out holding h0; only overwrite keep-graphs
// (#masked nodes > 1, via ballot).
__global__ __launch_bounds__(256) void epilogue_kernel(
    const float* __restrict__ g, const float* res,
    const float* __restrict__ ob, const float* __restrict__ lns,
    const float* __restrict__ lnb, const int* __restrict__ msk,
    float* hout, bf16* hb, int finalSel)
{
    const int lane = threadIdx.x & 63;
    const int wave = threadIdx.x >> 6;
    const int m = blockIdx.x * 4 + wave;
    if (finalSel) {
        const int gr = m >> 6;
        const int mv = msk[gr * NND + lane];
        const unsigned long long bal = __ballot(mv != 0);
        if (__popcll(bal) <= 1) return;   // leave h0 rows in d_out
    }
    const float* grow = g + (size_t)m * HID_;
    float v[4];
    float sum = 0.f;
    #pragma unroll
    for (int q = 0; q < 4; ++q) {
        const int c = q * 64 + lane;
        float x = grow[c] + ob[c];
        x = x > 0.f ? x : (__expf(x) - 1.f);   // ELU (alpha=1)
        v[q] = x; sum += x;
    }
    #pragma unroll
    for (int off = 1; off < 64; off <<= 1) sum += __shfl_xor(sum, off);
    const float mu = sum * (1.f / 256.f);
    float vs = 0.f;
    #pragma unroll
    for (int q = 0; q < 4; ++q) { const float d = v[q] - mu; vs += d * d; }
    #pragma unroll
    for (int off = 1; off < 64; off <<= 1) vs += __shfl_xor(vs, off);
    const float rstd = rsqrtf(vs * (1.f / 256.f) + LN_EPS_);
    const int mnode = msk[m];
    const float* rrow = res + (size_t)m * HID_;
    float* ho = hout + (size_t)m * HID_;
    #pragma unroll
    for (int q = 0; q < 4; ++q) {
        const int c = q * 64 + lane;
        float y = (v[q] - mu) * rstd * lns[c] + lnb[c];
        y += rrow[c];
        y = mnode ? y : 0.f;
        ho[c] = y;
        if (hb) hb[(size_t)m * HID_ + c] = __float2bfloat16(y);
    }
}

// ---------------------------------------------------------------------------
extern "C" void kernel_launch(void* const* d_in, const int* in_sizes, int n_in,
                              void* d_out, int out_size, void* d_ws, size_t ws_size,
                              hipStream_t stream) {
    const float* x    = (const float*)d_in[0];
    const float* W_in = (const float*)d_in[2];
    const float* b_in = (const float*)d_in[3];
    const float* Wl   = (const float*)d_in[4];
    const float* bl   = (const float*)d_in[5];
    const float* Wr   = (const float*)d_in[6];
    const float* br   = (const float*)d_in[7];
    const float* att  = (const float*)d_in[8];
    const float* ob   = (const float*)d_in[9];
    const float* lns  = (const float*)d_in[10];
    const float* lnb  = (const float*)d_in[11];
    float* out = (float*)d_out;

    // ws (~29 MB): [mcan 32K][h 8M][xlb 8M][xrb 8M][hxb 4M][WTin 256K][WlrT 512K]
    char* w = (char*)d_ws;
    int*   mcan = (int*)w;                      w += 32768;
    float* h    = (float*)w;                    w += (size_t)NROWS * HID_ * 4;
    float* xlb  = (float*)w;                    w += (size_t)NROWS * HID_ * 4;
    float* xrb  = (float*)w;                    w += (size_t)NROWS * HID_ * 4;
    bf16*  hxb  = (bf16*)w;                     w += (size_t)NROWS * HID_ * 2;
    bf16*  WTin = (bf16*)w;                     w += (size_t)D_IN_ * HID_ * 2;
    bf16*  WlrT = (bf16*)w;                     // [L][512][256]
    float* gb   = xrb;                          // aliased (safe — see attn_kernel)

    transpose_all_kernel<<<dim3(8, 16, 6), 256, 0, stream>>>(
        W_in, Wl, Wr, (const unsigned int*)d_in[1], WTin, WlrT, mcan);

    // d_out <- fp32 h0 = x @ W_in + b_in ; hxb <- bf16(h0)
    gemm_in_kernel<<<dim3(HID_ / 64, NROWS / 64), 256, 0, stream>>>(
        x, WTin, b_in, out, hxb);

    for (int li = 0; li < 2; ++li) {
        const float* resf = (li == 0) ? out : h;   // fp32 residual
        gemm_mfma_kernel<<<dim3(512 / 64, NROWS / 128), 256, 0, stream>>>(
            hxb, WlrT + (size_t)li * 512 * HID_, bl + li * HID_, br + li * HID_,
            xlb, xrb, NROWS, HID_);
        attn_kernel<<<dim3(NH * 2, BT_G), 256, 0, stream>>>(
            xlb, xrb, att + li * NH * NCH, mcan, gb);
        if (li == 0) {
            epilogue_kernel<<<NROWS / 4, 256, 0, stream>>>(
                gb, resf, ob, lns, lnb, mcan, h, hxb, 0);
        } else {
            epilogue_kernel<<<NROWS / 4, 256, 0, stream>>>(
                gb, resf, ob + HID_, lns + HID_, lnb + HID_, mcan,
                out, (bf16*)nullptr, 1);
        }
    }

    (void)in_sizes; (void)n_in; (void)out_size; (void)ws_size;
}